// Round 15
// baseline (947.046 us; speedup 1.0000x reference)
//
#include <hip/hip_runtime.h>
#include <stdint.h>

// LPDNet forward on gfx950.
// Layout decisions:
//   hb16/hlo16 : (B,N,64) bf16 hi/lo split of h -> MFMA knn + pure-copy gather
//   featb : (B,N,512) bf16 rows -> [x1 | x2 | x3]; feeds conv3 GEMM and x2 gather
//   idx1/idx2 : (B,N,20) int32
// Graph-conv trick: W·[nbr-ctr | ctr] == W'·[nbr | ctr] with W' = [Wn | Wc-Wn]
// (transformed once in cvt_weights) -> gather staging is pure short8 copies.
// knn64: inner products via 4-term split-bf16 MFMA (hi/lo), residual ~1e-8.
// bf16 conv path (fp32 accum); tolerance is 2% of max|ref|.
// Ledger: R15 943 (knn 422); R18 u16-maxpool 931 BEST (knn 421).
// R19: knn64 drops m-tile LDS staging entirely. B-data (4MB hi+lo) is
// L2-resident -- staging only converted L2 reads into LDS write+read pairs
// (+1.97e7 bank conflicts). MFMA B-fragments now load directly from global
// (16B-aligned dwordx4, L2 hit, 16 in flight per tile); xm loads directly
// from XX. Deletes the staging phase, mhi/mlo/xxMh arrays, and their
// addressing; 2 barriers/tile remain (dots buffer). Cost: 4x redundant L2
// reads (~2GB over kernel ~ 60us aggregate L2 BW, non-binding).

#define NB 8
#define NP 4096
#define NPTS (NB*NP)

typedef float  floatx4 __attribute__((ext_vector_type(4)));
typedef short  short8  __attribute__((ext_vector_type(8)));
typedef unsigned short u16x4 __attribute__((ext_vector_type(4)));

__device__ __forceinline__ unsigned short f2bf(float f) {
  union { float f; uint32_t u; } v; v.f = f;
  uint32_t r = v.u + 0x7fffu + ((v.u >> 16) & 1u);   // RNE
  return (unsigned short)(r >> 16);
}
__device__ __forceinline__ float bf2f(unsigned short h) {
  union { uint32_t u; float f; } v; v.u = ((uint32_t)h) << 16;
  return v.f;
}
__device__ __forceinline__ u16x4 max4(u16x4 a, u16x4 b) {
  u16x4 r;
  r[0] = a[0] > b[0] ? a[0] : b[0];
  r[1] = a[1] > b[1] ? a[1] : b[1];
  r[2] = a[2] > b[2] ? a[2] : b[2];
  r[3] = a[3] > b[3] ? a[3] : b[3];
  return r;
}

__device__ __forceinline__ floatx4 mfma_bf16(short8 a, short8 b, floatx4 c) {
  return __builtin_amdgcn_mfma_f32_16x16x32_bf16(a, b, c, 0, 0, 0);
}

// ---------------- K0: weight conversion + graph-fold transform ---------------
__global__ void cvt_weights(const float* wdg1, unsigned short* wdg1b,
                            const float* wdg2, unsigned short* wdg2b,
                            const float* wsn1, unsigned short* wsn1b,
                            const float* w3, unsigned short* w3b) {
  int i = blockIdx.x * 256 + threadIdx.x;
  if (i < 16384) {                       // wdg1' = [Wn | Wc-Wn], C=64
    int c = i & 127;
    wdg1b[i] = f2bf(wdg1[i] - (c >= 64 ? wdg1[i - 64] : 0.f));
  }
  if (i < 16384) wdg2b[i] = f2bf(wdg2[i]);
  if (i < 65536) {                       // wsn1' = [Wn | Wc-Wn], C=128
    int c = i & 255;
    wsn1b[i] = f2bf(wsn1[i] - (c >= 128 ? wsn1[i - 128] : 0.f));
  }
  if (i < 524288) w3b[i] = f2bf(w3[i]);
}

// ---------------- K1: conv1+relu, conv2+relu -> h hi/lo bf16, xx sums --------
__global__ __launch_bounds__(256) void conv12(
    const float* __restrict__ xin, const float* __restrict__ w1,
    const float* __restrict__ b1, const float* __restrict__ w2,
    const float* __restrict__ b2,
    unsigned short* __restrict__ hb16, unsigned short* __restrict__ hlo16,
    float* __restrict__ hh, float* __restrict__ cc) {
  int wave = threadIdx.x >> 6, lane = threadIdx.x & 63;
  int p = blockIdx.x * 4 + wave;                    // grid 8192
  __shared__ float s_h1[4][64];
  const float* xp = xin + p * 3;
  float c0 = xp[0], c1 = xp[1], c2 = xp[2];
  float v = b1[lane] + w1[lane*3+0]*c0 + w1[lane*3+1]*c1 + w1[lane*3+2]*c2;
  s_h1[wave][lane] = fmaxf(v, 0.f);
  __syncthreads();
  float acc = b2[lane];
  const float* wr = w2 + lane * 64;
  #pragma unroll
  for (int c = 0; c < 64; c += 4) {
    floatx4 w4 = *(const floatx4*)(wr + c);
    acc += w4[0]*s_h1[wave][c]   + w4[1]*s_h1[wave][c+1]
         + w4[2]*s_h1[wave][c+2] + w4[3]*s_h1[wave][c+3];
  }
  acc = fmaxf(acc, 0.f);
  unsigned short hi = f2bf(acc);
  hb16[p*64 + lane] = hi;
  hlo16[p*64 + lane] = f2bf(acc - bf2f(hi));
  float sq = acc * acc;
  #pragma unroll
  for (int off = 32; off; off >>= 1) sq += __shfl_xor(sq, off, 64);
  if (lane == 0) { hh[p] = sq; cc[p] = c0*c0 + c1*c1 + c2*c2; }
}

// ---------------- K2: fused knn (knn64 direct-L2 | knn3 128-wide) ------------
// LDS arena overlays (36,960 B max -> 4 blocks/CU):
//   knn64 : dots[64][68]f32 @0 (17,408 B only -- staging removed)
//   knn3  : rowsT[3][68]f32 @0, mT[3][132] @816, dots[64][132] @2400,
//           xxMh[128] @36192 (36,704 B)
// All row strides 16B-aligned.

__device__ __forceinline__ void knn64_body(
    unsigned char* smem,
    const unsigned short* __restrict__ Hhi, const unsigned short* __restrict__ Hlo,
    const float* __restrict__ XX, int* __restrict__ idx_out,
    int xt, int b) {
  auto dots = (float (*)[68])(smem);
  int r0 = xt * 64;
  int t = threadIdx.x;
  int lane = t & 63, wave = t >> 6;
  int quad = lane >> 4, l15 = lane & 15;
  const unsigned short* Hhib = Hhi + (size_t)b * NP * 64;
  const unsigned short* Hlob = Hlo + (size_t)b * NP * 64;
  const float* XXb = XX + (size_t)b * NP;
  short8 ahi[2], alo[2];
  {
    const unsigned short* pr = Hhib + (size_t)(r0 + wave * 16 + l15) * 64 + quad * 8;
    const unsigned short* pl = Hlob + (size_t)(r0 + wave * 16 + l15) * 64 + quad * 8;
    ahi[0] = *(const short8*)pr; ahi[1] = *(const short8*)(pr + 32);
    alo[0] = *(const short8*)pl; alo[1] = *(const short8*)(pl + 32);
  }

  float lv[20]; int li[20];
  #pragma unroll
  for (int s = 0; s < 20; s++) { lv[s] = -__builtin_inff(); li[s] = 0x7fffffff; }
  float minval = -__builtin_inff(); int minpos = 0;
  float tau_reg = -__builtin_inff();
  int row = t >> 2, sub = t & 3;

  for (int mt = 0; mt < NP / 64; mt++) {
    int m0 = mt * 64;
    __syncthreads();                       // previous selection done (dots free)
    #pragma unroll
    for (int nt = 0; nt < 4; nt++) {
      int brow = m0 + nt * 16 + l15;
      const unsigned short* bh = Hhib + (size_t)brow * 64;
      const unsigned short* bl = Hlob + (size_t)brow * 64;
      floatx4 acc = (floatx4)0.f;
      #pragma unroll
      for (int ks = 0; ks < 2; ks++) {
        int k0 = ks * 32 + quad * 8;
        short8 bhi = *(const short8*)(bh + k0);   // direct L2 hit
        short8 blo = *(const short8*)(bl + k0);
        acc = mfma_bf16(ahi[ks], bhi, acc);
        acc = mfma_bf16(ahi[ks], blo, acc);
        acc = mfma_bf16(alo[ks], bhi, acc);
        acc = mfma_bf16(alo[ks], blo, acc);
      }
      int colg = nt * 16 + l15;
      float xm = 0.5f * XXb[m0 + colg];
      #pragma unroll
      for (int r = 0; r < 4; r++) {
        int mr = wave * 16 + quad * 4 + r;
        dots[mr][colg] = acc[r] - xm;
      }
    }
    __syncthreads();                       // dots ready
    // ---- ballot selection, row-consensus register gate ----
    float gate = fmaxf(minval, tau_reg);
    floatx4 dv0 = *(floatx4*)&dots[row][sub * 16];
    floatx4 dv1 = *(floatx4*)&dots[row][sub * 16 + 4];
    floatx4 dv2 = *(floatx4*)&dots[row][sub * 16 + 8];
    floatx4 dv3 = *(floatx4*)&dots[row][sub * 16 + 12];
    uint32_t mask = 0;
    #pragma unroll
    for (int j = 0; j < 4; j++) {
      if (dv0[j] > gate) mask |= 1u << j;
      if (dv1[j] > gate) mask |= 1u << (4 + j);
      if (dv2[j] > gate) mask |= 1u << (8 + j);
      if (dv3[j] > gate) mask |= 1u << (12 + j);
    }
    #pragma clang loop unroll(disable)
    for (int round = 0; round < 16; round++) {
      if (!__any(mask != 0)) break;
      if (mask) {
        int i = __builtin_ctz(mask); mask &= mask - 1;
        float v = dots[row][sub * 16 + i];
        if (v > minval) {
          int gi = m0 + sub * 16 + i;
          #pragma unroll
          for (int s = 0; s < 20; s++)
            if (s == minpos) { lv[s] = v; li[s] = gi; }
          minval = __builtin_inff();
          #pragma unroll
          for (int s = 0; s < 20; s++)
            if (lv[s] < minval) { minval = lv[s]; minpos = s; }
        }
      }
    }
    // row-consensus gate: max over the 4 sub-threads' local 20th-best
    float g = minval;
    g = fmaxf(g, __shfl_xor(g, 1, 64));
    g = fmaxf(g, __shfl_xor(g, 2, 64));
    tau_reg = g;
  }
  int base = (b * NP + r0 + row) * 20;
  for (int sel = 0; sel < 20; sel++) {
    float mybv = -__builtin_inff(); int mybi = 0x7fffffff, mybs = 0;
    #pragma unroll
    for (int s = 0; s < 20; s++) {
      bool better = lv[s] > mybv || (lv[s] == mybv && li[s] < mybi);
      if (better) { mybv = lv[s]; mybi = li[s]; mybs = s; }
    }
    float bv = mybv; int bi = mybi;
    float ov = __shfl_xor(bv, 1, 64); int oi = __shfl_xor(bi, 1, 64);
    if (ov > bv || (ov == bv && oi < bi)) { bv = ov; bi = oi; }
    ov = __shfl_xor(bv, 2, 64); oi = __shfl_xor(bi, 2, 64);
    if (ov > bv || (ov == bv && oi < bi)) { bv = ov; bi = oi; }
    if (sub == 0) idx_out[base + sel] = bi;
    if (bi == mybi) {
      #pragma unroll
      for (int s = 0; s < 20; s++)
        if (s == mybs) { lv[s] = -__builtin_inff(); li[s] = 0x7fffffff; }
    }
  }
}

__device__ __forceinline__ void knn3_body(
    unsigned char* smem,
    const float* __restrict__ X, const float* __restrict__ XX,
    int* __restrict__ idx_out, int xt, int b) {
  constexpr int C = 3;
  auto rowsT = (float (*)[68])(smem);
  auto mT    = (float (*)[132])(smem + 816);
  auto dots  = (float (*)[132])(smem + 2400);
  float* xxMh = (float*)(smem + 36192);
  int r0 = xt * 64;
  int t = threadIdx.x;
  const float* Xb = X + (size_t)b * NP * C;
  for (int e = t; e < C * 64; e += 256) {
    int r = e / C, c = e - r * C;
    rowsT[c][r] = Xb[(r0 + r) * C + c];
  }

  float lv[20]; int li[20];
  #pragma unroll
  for (int s = 0; s < 20; s++) { lv[s] = -__builtin_inff(); li[s] = 0x7fffffff; }
  float minval = -__builtin_inff(); int minpos = 0;
  float tau_reg = -__builtin_inff();

  int tm = t & 15, tr = t >> 4;
  int row = t >> 2, sub = t & 3;

  for (int mt = 0; mt < NP / 128; mt++) {
    int m0 = mt * 128;
    for (int e = t; e < C * 128; e += 256) {
      int r = e / C, c = e - r * C;
      mT[c][r] = Xb[(m0 + r) * C + c];
    }
    if (t < 128) xxMh[t] = 0.5f * XX[b * NP + m0 + t];
    __syncthreads();
    float acc[4][8];
    #pragma unroll
    for (int i = 0; i < 4; i++)
      #pragma unroll
      for (int j = 0; j < 8; j++) acc[i][j] = 0.f;
    for (int c = 0; c < C; c++) {
      floatx4 av  = *(floatx4*)&rowsT[c][tr * 4];
      floatx4 bv0 = *(floatx4*)&mT[c][tm * 8];
      floatx4 bv1 = *(floatx4*)&mT[c][tm * 8 + 4];
      #pragma unroll
      for (int i = 0; i < 4; i++)
        #pragma unroll
        for (int j = 0; j < 4; j++) {
          acc[i][j]     += av[i] * bv0[j];
          acc[i][j + 4] += av[i] * bv1[j];
        }
    }
    #pragma unroll
    for (int i = 0; i < 4; i++) {
      floatx4 sv0, sv1;
      #pragma unroll
      for (int j = 0; j < 4; j++) {
        sv0[j] = acc[i][j]     - xxMh[tm*8 + j];
        sv1[j] = acc[i][j + 4] - xxMh[tm*8 + 4 + j];
      }
      *(floatx4*)&dots[tr*4 + i][tm*8]     = sv0;
      *(floatx4*)&dots[tr*4 + i][tm*8 + 4] = sv1;
    }
    __syncthreads();
    // ---- selection, 32 cols per sub-thread, register gate ----
    float gate = fmaxf(minval, tau_reg);
    floatx4 dv[8];
    #pragma unroll
    for (int q = 0; q < 8; q++) dv[q] = *(floatx4*)&dots[row][sub * 32 + q * 4];
    uint32_t mask = 0;
    #pragma unroll
    for (int q = 0; q < 8; q++)
      #pragma unroll
      for (int j = 0; j < 4; j++)
        if (dv[q][j] > gate) mask |= 1u << (q * 4 + j);
    #pragma clang loop unroll(disable)
    for (int round = 0; round < 32; round++) {
      if (!__any(mask != 0)) break;
      if (mask) {
        int i = __builtin_ctz(mask); mask &= mask - 1;
        float v = dots[row][sub * 32 + i];
        if (v > minval) {
          int gi = m0 + sub * 32 + i;
          #pragma unroll
          for (int s = 0; s < 20; s++)
            if (s == minpos) { lv[s] = v; li[s] = gi; }
          minval = __builtin_inff();
          #pragma unroll
          for (int s = 0; s < 20; s++)
            if (lv[s] < minval) { minval = lv[s]; minpos = s; }
        }
      }
    }
    float g = minval;
    g = fmaxf(g, __shfl_xor(g, 1, 64));
    g = fmaxf(g, __shfl_xor(g, 2, 64));
    tau_reg = g;
  }
  int base = (b * NP + r0 + row) * 20;
  for (int sel = 0; sel < 20; sel++) {
    float mybv = -__builtin_inff(); int mybi = 0x7fffffff, mybs = 0;
    #pragma unroll
    for (int s = 0; s < 20; s++) {
      bool better = lv[s] > mybv || (lv[s] == mybv && li[s] < mybi);
      if (better) { mybv = lv[s]; mybi = li[s]; mybs = s; }
    }
    float bv = mybv; int bi = mybi;
    float ov = __shfl_xor(bv, 1, 64); int oi = __shfl_xor(bi, 1, 64);
    if (ov > bv || (ov == bv && oi < bi)) { bv = ov; bi = oi; }
    ov = __shfl_xor(bv, 2, 64); oi = __shfl_xor(bi, 2, 64);
    if (ov > bv || (ov == bv && oi < bi)) { bv = ov; bi = oi; }
    if (sub == 0) idx_out[base + sel] = bi;
    if (bi == mybi) {
      #pragma unroll
      for (int s = 0; s < 20; s++)
        if (s == mybs) { lv[s] = -__builtin_inff(); li[s] = 0x7fffffff; }
    }
  }
}

__global__ __launch_bounds__(256) void knn_fused(
    const unsigned short* __restrict__ Hhi, const unsigned short* __restrict__ Hlo,
    const float* __restrict__ HH,
    const float* __restrict__ X, const float* __restrict__ CC,
    int* __restrict__ idx1, int* __restrict__ idx2) {
  __shared__ __attribute__((aligned(16))) unsigned char smem[36960];
  int id = blockIdx.x;                       // flat grid 1024
  int flavor = (id >> 8) & 1;                // slots {id,+256,+512,+768} ->
  int slot = (id & 255) | ((id >> 9) << 8);  // flavors {0,1,0,1} per CU
  int b = slot >> 6, xt = slot & 63;
  if (flavor == 0)
    knn64_body(smem, Hhi, Hlo, HH, idx1, xt, b);
  else
    knn3_body(smem, X, CC, idx2, xt, b);
}

// ---------------- K3: dg stage, 4 points/block, M=80 (zero padding) ----------
__global__ __launch_bounds__(256) void dg_stage(
    const unsigned short* __restrict__ hb16, const int* __restrict__ idx1,
    const unsigned short* __restrict__ w1b, const float* __restrict__ bia1,
    const unsigned short* __restrict__ w2b, const float* __restrict__ bia2,
    unsigned short* __restrict__ featb) {
  __shared__ unsigned short s_a[80][136];   // row stride 272 B (16B-aligned)
  __shared__ unsigned short s_v[80][136];
  __shared__ int s_nbf[80];
  int p0 = blockIdx.x * 4;                  // grid 8192; 4 pts share batch b
  int b = p0 >> 12, n0 = p0 & 4095;
  int t = threadIdx.x;
  int lane = t & 63, wave = t >> 6;
  if (t < 80) s_nbf[t] = idx1[p0 * 20 + t];
  __syncthreads();
  const unsigned short* hbb = hb16 + (size_t)b * NP * 64;
  {
    int cc = (t & 15) * 8;                  // uniform per-thread across iters
    int r00 = t >> 4;
    #pragma unroll
    for (int it = 0; it < 5; it++) {
      int row = r00 + it * 16;
      const unsigned short* src = (cc < 64)
        ? hbb + (size_t)s_nbf[row] * 64 + cc
        : hbb + (size_t)(n0 + row / 20) * 64 + (cc - 64);
      *(short8*)&s_a[row][cc] = *(const short8*)src;
    }
  }
  __syncthreads();
  int quad = lane >> 4, mrow = lane & 15;
  int nblock = wave * 32;
  // ---- dg1: A=s_a(80x128), W=w1b' ----
  {
    floatx4 acc[5][2];
    #pragma unroll
    for (int mt = 0; mt < 5; mt++) { acc[mt][0] = (floatx4)0.f; acc[mt][1] = (floatx4)0.f; }
    #pragma unroll
    for (int ks = 0; ks < 4; ks++) {
      int k0 = ks * 32 + quad * 8;
      short8 w0 = *(const short8*)(w1b + (nblock + mrow) * 128 + k0);
      short8 w1v = *(const short8*)(w1b + (nblock + 16 + mrow) * 128 + k0);
      #pragma unroll
      for (int mt = 0; mt < 5; mt++) {
        short8 a = *(short8*)&s_a[mt * 16 + mrow][k0];
        acc[mt][0] = mfma_bf16(a, w0, acc[mt][0]);
        acc[mt][1] = mfma_bf16(a, w1v, acc[mt][1]);
      }
    }
    #pragma unroll
    for (int ns = 0; ns < 2; ns++) {
      int o = nblock + ns * 16 + mrow;
      float bz = bia1[o];
      #pragma unroll
      for (int mt = 0; mt < 5; mt++)
        #pragma unroll
        for (int r = 0; r < 4; r++)
          s_v[mt * 16 + quad * 4 + r][o] = f2bf(fmaxf(acc[mt][ns][r] + bz, 0.f));
    }
  }
  __syncthreads();                          // s_v ready; all s_a reads done
  if (t < 128) {                            // maxpool1: u16 max (values >= 0)
    int pt = t >> 5, o4 = (t & 31) * 4;
    u16x4 mx = (u16x4)0;
    #pragma unroll
    for (int k = 0; k < 20; k++)
      mx = max4(mx, *(const u16x4*)&s_v[pt * 20 + k][o4]);
    *(u16x4*)&featb[(size_t)(p0 + pt) * 512 + o4] = mx;
  }
  // ---- dg2: A=s_v(80x128), W=w2b, relu -> s_a (reuse) ----
  {
    floatx4 acc[5][2];
    #pragma unroll
    for (int mt = 0; mt < 5; mt++) { acc[mt][0] = (floatx4)0.f; acc[mt][1] = (floatx4)0.f; }
    #pragma unroll
    for (int ks = 0; ks < 4; ks++) {
      int k0 = ks * 32 + quad * 8;
      short8 w0 = *(const short8*)(w2b + (nblock + mrow) * 128 + k0);
      short8 w1v = *(const short8*)(w2b + (nblock + 16 + mrow) * 128 + k0);
      #pragma unroll
      for (int mt = 0; mt < 5; mt++) {
        short8 a = *(short8*)&s_v[mt * 16 + mrow][k0];
        acc[mt][0] = mfma_bf16(a, w0, acc[mt][0]);
        acc[mt][1] = mfma_bf16(a, w1v, acc[mt][1]);
      }
    }
    #pragma unroll
    for (int ns = 0; ns < 2; ns++) {
      int o = nblock + ns * 16 + mrow;
      float bz = bia2[o];
      #pragma unroll
      for (int mt = 0; mt < 5; mt++)
        #pragma unroll
        for (int r = 0; r < 4; r++)
          s_a[mt * 16 + quad * 4 + r][o] = f2bf(fmaxf(acc[mt][ns][r] + bz, 0.f));
    }
  }
  __syncthreads();
  if (t < 128) {                            // maxpool2: u16 max
    int pt = t >> 5, o4 = (t & 31) * 4;
    u16x4 mx = (u16x4)0;
    #pragma unroll
    for (int k = 0; k < 20; k++)
      mx = max4(mx, *(const u16x4*)&s_a[pt * 20 + k][o4]);
    *(u16x4*)&featb[(size_t)(p0 + pt) * 512 + 128 + o4] = mx;
  }
}

// ---------------- K4: sn stage, 4 points/block, M=80 -------------------------
__global__ __launch_bounds__(256) void sn_stage(
    const int* __restrict__ idx2, const unsigned short* __restrict__ wb,
    const float* __restrict__ bias, unsigned short* __restrict__ featb) {
  __shared__ unsigned short s_a[80][264];   // row stride 528 B (16B-aligned)
  __shared__ int s_nbf[80];
  int p0 = blockIdx.x * 4;
  int b = p0 >> 12, n0 = p0 & 4095;
  int bb = b << 12;
  int t = threadIdx.x;
  int lane = t & 63, wave = t >> 6;
  if (t < 80) s_nbf[t] = idx2[p0 * 20 + t];
  __syncthreads();
  {
    int cc = (t & 31) * 8;                  // uniform per-thread
    int r00 = t >> 5;
    #pragma unroll
    for (int it = 0; it < 10; it++) {
      int row = r00 + it * 8;
      const unsigned short* src = (cc < 128)
        ? featb + (size_t)(bb + s_nbf[row]) * 512 + 128 + cc
        : featb + (size_t)(bb + n0 + row / 20) * 512 + cc;   // 128+(cc-128)
      *(short8*)&s_a[row][cc] = *(const short8*)src;
    }
  }
  __syncthreads();
  int quad = lane >> 4, mrow = lane & 15;
  int nblock = wave * 64;
  floatx4 acc[5][4];
  #pragma unroll
  for (int mt = 0; mt < 5; mt++)
    #pragma unroll
    for (int ns = 0; ns < 4; ns++) acc[mt][ns] = (floatx4)0.f;
  #pragma unroll
  for (int ks = 0; ks < 8; ks++) {
    int k0 = ks * 32 + quad * 8;
    short8 w[4];
    #pragma unroll
    for (int ns = 0; ns < 4; ns++)
      w[ns] = *(const short8*)(wb + (nblock + ns * 16 + mrow) * 256 + k0);
    #pragma unroll
    for (int mt = 0; mt < 5; mt++) {
      short8 a = *(short8*)&s_a[mt * 16 + mrow][k0];
      #pragma unroll
      for (int ns = 0; ns < 4; ns++)
        acc[mt][ns] = mfma_bf16(a, w[ns], acc[mt][ns]);
    }
  }
  __syncthreads();                          // all s_a reads done
  #pragma unroll
  for (int ns = 0; ns < 4; ns++) {
    int o = nblock + ns * 16 + mrow;
    float bz = bias[o];
    #pragma unroll
    for (int mt = 0; mt < 5; mt++)
      #pragma unroll
      for (int r = 0; r < 4; r++)
        s_a[mt * 16 + quad * 4 + r][o] = f2bf(fmaxf(acc[mt][ns][r] + bz, 0.f));
  }
  __syncthreads();
  {                                         // maxpool: u16 max (values >= 0)
    int pt = t >> 6, o4 = (t & 63) * 4;
    u16x4 mx = (u16x4)0;
    #pragma unroll
    for (int k = 0; k < 20; k++)
      mx = max4(mx, *(const u16x4*)&s_a[pt * 20 + k][o4]);
    *(u16x4*)&featb[(size_t)(p0 + pt) * 512 + 256 + o4] = mx;
  }
}

// ---------------- K5: conv3 GEMM ---------------------------------------------
__global__ __launch_bounds__(256) void conv3_gemm(
    const unsigned short* __restrict__ w3b, const unsigned short* __restrict__ featb,
    const float* __restrict__ b3, float* __restrict__ out) {
  __shared__ unsigned short s_a[128][40];
  __shared__ unsigned short s_b[128][40];
  int o0 = blockIdx.x * 128, p0 = blockIdx.y * 128;
  int t = threadIdx.x, lane = t & 63, wave = t >> 6;
  int wy = wave >> 1, wx = wave & 1;
  int quad = lane >> 4, l15 = lane & 15;
  floatx4 acc[4][4];
  #pragma unroll
  for (int i = 0; i < 4; i++)
    #pragma unroll
    for (int j = 0; j < 4; j++) acc[i][j] = (floatx4)0.f;
  for (int kc = 0; kc < 16; kc++) {
    __syncthreads();
    for (int e = t; e < 512; e += 256) {
      int r = e >> 2, c8 = (e & 3) * 8;
      *(short8*)&s_a[r][c8] = *(const short8*)(w3b + (size_t)(o0 + r) * 512 + kc * 32 + c8);
    }
    for (int e = t; e < 512; e += 256) {
      int r = e >> 2, c8 = (e & 3) * 8;
      *(short8*)&s_b[r][c8] = *(const short8*)(featb + (size_t)(p0 + r) * 512 + kc * 32 + c8);
    }
    __syncthreads();
    int k0 = quad * 8;
    short8 af[4], bfr[4];
    #pragma unroll
    for (int i = 0; i < 4; i++) af[i] = *(short8*)&s_a[wy * 64 + i * 16 + l15][k0];
    #pragma unroll
    for (int j = 0; j < 4; j++) bfr[j] = *(short8*)&s_b[wx * 64 + j * 16 + l15][k0];
    #pragma unroll
    for (int i = 0; i < 4; i++)
      #pragma unroll
      for (int j = 0; j < 4; j++) acc[i][j] = mfma_bf16(af[i], bfr[j], acc[i][j]);
  }
  #pragma unroll
  for (int i = 0; i < 4; i++)
    #pragma unroll
    for (int j = 0; j < 4; j++) {
      int pl = p0 + wx * 64 + j * 16 + l15;
      int bI = pl >> 12, n = pl & 4095;
      #pragma unroll
      for (int r = 0; r < 4; r++) {
        int o = o0 + wy * 64 + i * 16 + quad * 4 + r;
        out[(size_t)(bI * 1024 + o) * 4096 + n] = fmaxf(acc[i][j][r] + b3[o], 0.f);
      }
    }
}

// ---------------- launcher ---------------------------------------------------
extern "C" void kernel_launch(void* const* d_in, const int* in_sizes, int n_in,
                              void* d_out, int out_size, void* d_ws, size_t ws_size,
                              hipStream_t stream) {
  const float* x    = (const float*)d_in[0];
  const float* w1   = (const float*)d_in[1];
  const float* b1   = (const float*)d_in[2];
  const float* w2   = (const float*)d_in[3];
  const float* b2   = (const float*)d_in[4];
  const float* wdg1 = (const float*)d_in[5];
  const float* bdg1 = (const float*)d_in[6];
  const float* wdg2 = (const float*)d_in[7];
  const float* bdg2 = (const float*)d_in[8];
  const float* wsn1 = (const float*)d_in[9];
  const float* bsn1 = (const float*)d_in[10];
  const float* w3   = (const float*)d_in[11];
  const float* b3   = (const float*)d_in[12];

  float* ws = (float*)d_ws;                 // offsets in float slots
  unsigned short* hlo16 = (unsigned short*)ws;               // 2,097,152 bf16 (1,048,576 slots)
  float* hh = ws + 2097152;                 //    32,768
  float* cc = ws + 2129920;                 //    32,768
  int* idx1 = (int*)(ws + 2162688);         //   655,360
  int* idx2 = (int*)(ws + 2818048);         //   655,360
  unsigned short* featb = (unsigned short*)(ws + 3473408);   // 16,777,216 bf16
  unsigned short* wdg1b = (unsigned short*)(ws + 11862016);
  unsigned short* wdg2b = (unsigned short*)(ws + 11870208);
  unsigned short* wsn1b = (unsigned short*)(ws + 11878400);
  unsigned short* w3b   = (unsigned short*)(ws + 11911168);
  unsigned short* hb16  = (unsigned short*)(ws + 12173312); // 2,097,152 bf16

  cvt_weights<<<2048, 256, 0, stream>>>(wdg1, wdg1b, wdg2, wdg2b,
                                        wsn1, wsn1b, w3, w3b);
  conv12<<<8192, 256, 0, stream>>>(x, w1, b1, w2, b2, hb16, hlo16, hh, cc);
  knn_fused<<<1024, 256, 0, stream>>>(hb16, hlo16, hh, x, cc, idx1, idx2);
  dg_stage<<<8192, 256, 0, stream>>>(hb16, idx1, wdg1b, bdg1, wdg2b, bdg2, featb);
  sn_stage<<<8192, 256, 0, stream>>>(idx2, wsn1b, bsn1, featb);
  conv3_gemm<<<dim3(8, 256), 256, 0, stream>>>(w3b, featb, b3, (float*)d_out);
}

// Round 16
// 928.722 us; speedup vs baseline: 1.0197x; 1.0197x over previous
//
#include <hip/hip_runtime.h>
#include <stdint.h>

// LPDNet forward on gfx950.
// Layout decisions:
//   hb16/hlo16 : (B,N,64) bf16 hi/lo split of h -> MFMA knn + pure-copy gather
//   featb : (B,N,512) bf16 rows -> [x1 | x2 | x3]; feeds conv3 GEMM and x2 gather
//   idx1/idx2 : (B,N,20) int32
// Graph-conv trick: W·[nbr-ctr | ctr] == W'·[nbr | ctr] with W' = [Wn | Wc-Wn]
// (transformed once in the cvt flavor) -> gather staging is pure short8 copies.
// knn64: inner products via 4-term split-bf16 MFMA (hi/lo), residual ~1e-8.
// bf16 conv path (fp32 accum); tolerance is 2% of max|ref|.
// Ledger: R18 = 931 BEST (knn_fused 421, u16 maxpool). R19 direct-L2 knn64
// REGRESSED (441/947): VALU-cycles identical (staging VALU ~= global-addr
// VALU), conflicts weren't binding, +20us exposed L2 latency. Reverted.
// knn plateau: 420-443 across 6 variants, ~278us-equiv VALU issue @63-66%.
// R20: R18 verbatim + cvt_weights fused into conv12's dispatch (grid 10240,
// ids>=8192 run cvt). cvt is independent of conv12 (weights vs x) and first
// consumed by dg_stage 3 launches later; same-kernel completion preserves
// ordering. Saves one launch + overlaps cvt's memory work.

#define NB 8
#define NP 4096
#define NPTS (NB*NP)

typedef float  floatx4 __attribute__((ext_vector_type(4)));
typedef short  short8  __attribute__((ext_vector_type(8)));
typedef unsigned short u16x4 __attribute__((ext_vector_type(4)));

__device__ __forceinline__ unsigned short f2bf(float f) {
  union { float f; uint32_t u; } v; v.f = f;
  uint32_t r = v.u + 0x7fffu + ((v.u >> 16) & 1u);   // RNE
  return (unsigned short)(r >> 16);
}
__device__ __forceinline__ float bf2f(unsigned short h) {
  union { uint32_t u; float f; } v; v.u = ((uint32_t)h) << 16;
  return v.f;
}
__device__ __forceinline__ u16x4 max4(u16x4 a, u16x4 b) {
  u16x4 r;
  r[0] = a[0] > b[0] ? a[0] : b[0];
  r[1] = a[1] > b[1] ? a[1] : b[1];
  r[2] = a[2] > b[2] ? a[2] : b[2];
  r[3] = a[3] > b[3] ? a[3] : b[3];
  return r;
}

__device__ __forceinline__ floatx4 mfma_bf16(short8 a, short8 b, floatx4 c) {
  return __builtin_amdgcn_mfma_f32_16x16x32_bf16(a, b, c, 0, 0, 0);
}

// ---------------- K1: conv1+conv2 (ids<8192) | weight-cvt (ids>=8192) --------
__global__ __launch_bounds__(256) void conv12_cvt(
    const float* __restrict__ xin, const float* __restrict__ w1,
    const float* __restrict__ b1, const float* __restrict__ w2,
    const float* __restrict__ b2,
    unsigned short* __restrict__ hb16, unsigned short* __restrict__ hlo16,
    float* __restrict__ hh, float* __restrict__ cc,
    const float* __restrict__ wdg1, unsigned short* __restrict__ wdg1b,
    const float* __restrict__ wdg2, unsigned short* __restrict__ wdg2b,
    const float* __restrict__ wsn1, unsigned short* __restrict__ wsn1b,
    const float* __restrict__ w3, unsigned short* __restrict__ w3b) {
  int bid = blockIdx.x;
  if (bid >= 8192) {                       // ---- cvt flavor (2048 blocks) ----
    int i = (bid - 8192) * 256 + threadIdx.x;
    if (i < 16384) {                       // wdg1' = [Wn | Wc-Wn], C=64
      int c = i & 127;
      wdg1b[i] = f2bf(wdg1[i] - (c >= 64 ? wdg1[i - 64] : 0.f));
    }
    if (i < 16384) wdg2b[i] = f2bf(wdg2[i]);
    if (i < 65536) {                       // wsn1' = [Wn | Wc-Wn], C=128
      int c = i & 255;
      wsn1b[i] = f2bf(wsn1[i] - (c >= 128 ? wsn1[i - 128] : 0.f));
    }
    if (i < 524288) w3b[i] = f2bf(w3[i]);
    return;
  }
  // ---- conv12 flavor ----
  int wave = threadIdx.x >> 6, lane = threadIdx.x & 63;
  int p = bid * 4 + wave;                  // 8192 blocks x 4 pts
  __shared__ float s_h1[4][64];
  const float* xp = xin + p * 3;
  float c0 = xp[0], c1 = xp[1], c2 = xp[2];
  float v = b1[lane] + w1[lane*3+0]*c0 + w1[lane*3+1]*c1 + w1[lane*3+2]*c2;
  s_h1[wave][lane] = fmaxf(v, 0.f);
  __syncthreads();
  float acc = b2[lane];
  const float* wr = w2 + lane * 64;
  #pragma unroll
  for (int c = 0; c < 64; c += 4) {
    floatx4 w4 = *(const floatx4*)(wr + c);
    acc += w4[0]*s_h1[wave][c]   + w4[1]*s_h1[wave][c+1]
         + w4[2]*s_h1[wave][c+2] + w4[3]*s_h1[wave][c+3];
  }
  acc = fmaxf(acc, 0.f);
  unsigned short hi = f2bf(acc);
  hb16[p*64 + lane] = hi;
  hlo16[p*64 + lane] = f2bf(acc - bf2f(hi));
  float sq = acc * acc;
  #pragma unroll
  for (int off = 32; off; off >>= 1) sq += __shfl_xor(sq, off, 64);
  if (lane == 0) { hh[p] = sq; cc[p] = c0*c0 + c1*c1 + c2*c2; }
}

// ---------------- K2: fused knn (knn64 64-wide | knn3 128-wide) --------------
// LDS arena overlays (36,960 B max -> 4 blocks/CU):
//   knn64 : mhi[64][72]u16 @0, mlo @9216, dots[64][68]f32 @18432,
//           xxMh[64] @35840  (36,096 B)
//   knn3  : rowsT[3][68]f32 @0, mT[3][132] @816, dots[64][132] @2400,
//           xxMh[128] @36192 (36,704 B)
// All row strides 16B-aligned.

__device__ __forceinline__ void knn64_body(
    unsigned char* smem,
    const unsigned short* __restrict__ Hhi, const unsigned short* __restrict__ Hlo,
    const float* __restrict__ XX, int* __restrict__ idx_out,
    int xt, int b) {
  auto mhi  = (unsigned short (*)[72])(smem);
  auto mlo  = (unsigned short (*)[72])(smem + 9216);
  auto dots = (float (*)[68])(smem + 18432);
  float* xxMh = (float*)(smem + 35840);
  int r0 = xt * 64;
  int t = threadIdx.x;
  int lane = t & 63, wave = t >> 6;
  int quad = lane >> 4, l15 = lane & 15;
  const unsigned short* Hhib = Hhi + (size_t)b * NP * 64;
  const unsigned short* Hlob = Hlo + (size_t)b * NP * 64;
  short8 ahi[2], alo[2];
  {
    const unsigned short* pr = Hhib + (size_t)(r0 + wave * 16 + l15) * 64 + quad * 8;
    const unsigned short* pl = Hlob + (size_t)(r0 + wave * 16 + l15) * 64 + quad * 8;
    ahi[0] = *(const short8*)pr; ahi[1] = *(const short8*)(pr + 32);
    alo[0] = *(const short8*)pl; alo[1] = *(const short8*)(pl + 32);
  }

  float lv[20]; int li[20];
  #pragma unroll
  for (int s = 0; s < 20; s++) { lv[s] = -__builtin_inff(); li[s] = 0x7fffffff; }
  float minval = -__builtin_inff(); int minpos = 0;
  float tau_reg = -__builtin_inff();
  int row = t >> 2, sub = t & 3;

  for (int mt = 0; mt < NP / 64; mt++) {
    int m0 = mt * 64;
    {                                      // stage m-tile hi/lo (pure copies)
      int pt = t >> 2, c0 = (t & 3) * 16;
      const unsigned short* sh = Hhib + (size_t)(m0 + pt) * 64 + c0;
      const unsigned short* sl = Hlob + (size_t)(m0 + pt) * 64 + c0;
      *(short8*)&mhi[pt][c0]     = *(const short8*)sh;
      *(short8*)&mhi[pt][c0 + 8] = *(const short8*)(sh + 8);
      *(short8*)&mlo[pt][c0]     = *(const short8*)sl;
      *(short8*)&mlo[pt][c0 + 8] = *(const short8*)(sl + 8);
    }
    if (t < 64) xxMh[t] = 0.5f * XX[b * NP + m0 + t];
    __syncthreads();                       // staging visible; prev select done
    #pragma unroll
    for (int nt = 0; nt < 4; nt++) {
      floatx4 acc = (floatx4)0.f;
      #pragma unroll
      for (int ks = 0; ks < 2; ks++) {
        int k0 = ks * 32 + quad * 8;
        short8 bhi = *(short8*)&mhi[nt * 16 + l15][k0];
        short8 blo = *(short8*)&mlo[nt * 16 + l15][k0];
        acc = mfma_bf16(ahi[ks], bhi, acc);
        acc = mfma_bf16(ahi[ks], blo, acc);
        acc = mfma_bf16(alo[ks], bhi, acc);
        acc = mfma_bf16(alo[ks], blo, acc);
      }
      int colg = nt * 16 + l15;
      float xm = xxMh[colg];
      #pragma unroll
      for (int r = 0; r < 4; r++) {
        int mr = wave * 16 + quad * 4 + r;
        dots[mr][colg] = acc[r] - xm;
      }
    }
    __syncthreads();                       // dots ready
    // ---- ballot selection, row-consensus register gate ----
    float gate = fmaxf(minval, tau_reg);
    floatx4 dv0 = *(floatx4*)&dots[row][sub * 16];
    floatx4 dv1 = *(floatx4*)&dots[row][sub * 16 + 4];
    floatx4 dv2 = *(floatx4*)&dots[row][sub * 16 + 8];
    floatx4 dv3 = *(floatx4*)&dots[row][sub * 16 + 12];
    uint32_t mask = 0;
    #pragma unroll
    for (int j = 0; j < 4; j++) {
      if (dv0[j] > gate) mask |= 1u << j;
      if (dv1[j] > gate) mask |= 1u << (4 + j);
      if (dv2[j] > gate) mask |= 1u << (8 + j);
      if (dv3[j] > gate) mask |= 1u << (12 + j);
    }
    #pragma clang loop unroll(disable)
    for (int round = 0; round < 16; round++) {
      if (!__any(mask != 0)) break;
      if (mask) {
        int i = __builtin_ctz(mask); mask &= mask - 1;
        float v = dots[row][sub * 16 + i];
        if (v > minval) {
          int gi = m0 + sub * 16 + i;
          #pragma unroll
          for (int s = 0; s < 20; s++)
            if (s == minpos) { lv[s] = v; li[s] = gi; }
          minval = __builtin_inff();
          #pragma unroll
          for (int s = 0; s < 20; s++)
            if (lv[s] < minval) { minval = lv[s]; minpos = s; }
        }
      }
    }
    // row-consensus gate: max over the 4 sub-threads' local 20th-best
    float g = minval;
    g = fmaxf(g, __shfl_xor(g, 1, 64));
    g = fmaxf(g, __shfl_xor(g, 2, 64));
    tau_reg = g;
  }
  int base = (b * NP + r0 + row) * 20;
  for (int sel = 0; sel < 20; sel++) {
    float mybv = -__builtin_inff(); int mybi = 0x7fffffff, mybs = 0;
    #pragma unroll
    for (int s = 0; s < 20; s++) {
      bool better = lv[s] > mybv || (lv[s] == mybv && li[s] < mybi);
      if (better) { mybv = lv[s]; mybi = li[s]; mybs = s; }
    }
    float bv = mybv; int bi = mybi;
    float ov = __shfl_xor(bv, 1, 64); int oi = __shfl_xor(bi, 1, 64);
    if (ov > bv || (ov == bv && oi < bi)) { bv = ov; bi = oi; }
    ov = __shfl_xor(bv, 2, 64); oi = __shfl_xor(bi, 2, 64);
    if (ov > bv || (ov == bv && oi < bi)) { bv = ov; bi = oi; }
    if (sub == 0) idx_out[base + sel] = bi;
    if (bi == mybi) {
      #pragma unroll
      for (int s = 0; s < 20; s++)
        if (s == mybs) { lv[s] = -__builtin_inff(); li[s] = 0x7fffffff; }
    }
  }
}

__device__ __forceinline__ void knn3_body(
    unsigned char* smem,
    const float* __restrict__ X, const float* __restrict__ XX,
    int* __restrict__ idx_out, int xt, int b) {
  constexpr int C = 3;
  auto rowsT = (float (*)[68])(smem);
  auto mT    = (float (*)[132])(smem + 816);
  auto dots  = (float (*)[132])(smem + 2400);
  float* xxMh = (float*)(smem + 36192);
  int r0 = xt * 64;
  int t = threadIdx.x;
  const float* Xb = X + (size_t)b * NP * C;
  for (int e = t; e < C * 64; e += 256) {
    int r = e / C, c = e - r * C;
    rowsT[c][r] = Xb[(r0 + r) * C + c];
  }

  float lv[20]; int li[20];
  #pragma unroll
  for (int s = 0; s < 20; s++) { lv[s] = -__builtin_inff(); li[s] = 0x7fffffff; }
  float minval = -__builtin_inff(); int minpos = 0;
  float tau_reg = -__builtin_inff();

  int tm = t & 15, tr = t >> 4;
  int row = t >> 2, sub = t & 3;

  for (int mt = 0; mt < NP / 128; mt++) {
    int m0 = mt * 128;
    for (int e = t; e < C * 128; e += 256) {
      int r = e / C, c = e - r * C;
      mT[c][r] = Xb[(m0 + r) * C + c];
    }
    if (t < 128) xxMh[t] = 0.5f * XX[b * NP + m0 + t];
    __syncthreads();
    float acc[4][8];
    #pragma unroll
    for (int i = 0; i < 4; i++)
      #pragma unroll
      for (int j = 0; j < 8; j++) acc[i][j] = 0.f;
    for (int c = 0; c < C; c++) {
      floatx4 av  = *(floatx4*)&rowsT[c][tr * 4];
      floatx4 bv0 = *(floatx4*)&mT[c][tm * 8];
      floatx4 bv1 = *(floatx4*)&mT[c][tm * 8 + 4];
      #pragma unroll
      for (int i = 0; i < 4; i++)
        #pragma unroll
        for (int j = 0; j < 4; j++) {
          acc[i][j]     += av[i] * bv0[j];
          acc[i][j + 4] += av[i] * bv1[j];
        }
    }
    #pragma unroll
    for (int i = 0; i < 4; i++) {
      floatx4 sv0, sv1;
      #pragma unroll
      for (int j = 0; j < 4; j++) {
        sv0[j] = acc[i][j]     - xxMh[tm*8 + j];
        sv1[j] = acc[i][j + 4] - xxMh[tm*8 + 4 + j];
      }
      *(floatx4*)&dots[tr*4 + i][tm*8]     = sv0;
      *(floatx4*)&dots[tr*4 + i][tm*8 + 4] = sv1;
    }
    __syncthreads();
    // ---- selection, 32 cols per sub-thread, register gate ----
    float gate = fmaxf(minval, tau_reg);
    floatx4 dv[8];
    #pragma unroll
    for (int q = 0; q < 8; q++) dv[q] = *(floatx4*)&dots[row][sub * 32 + q * 4];
    uint32_t mask = 0;
    #pragma unroll
    for (int q = 0; q < 8; q++)
      #pragma unroll
      for (int j = 0; j < 4; j++)
        if (dv[q][j] > gate) mask |= 1u << (q * 4 + j);
    #pragma clang loop unroll(disable)
    for (int round = 0; round < 32; round++) {
      if (!__any(mask != 0)) break;
      if (mask) {
        int i = __builtin_ctz(mask); mask &= mask - 1;
        float v = dots[row][sub * 32 + i];
        if (v > minval) {
          int gi = m0 + sub * 32 + i;
          #pragma unroll
          for (int s = 0; s < 20; s++)
            if (s == minpos) { lv[s] = v; li[s] = gi; }
          minval = __builtin_inff();
          #pragma unroll
          for (int s = 0; s < 20; s++)
            if (lv[s] < minval) { minval = lv[s]; minpos = s; }
        }
      }
    }
    float g = minval;
    g = fmaxf(g, __shfl_xor(g, 1, 64));
    g = fmaxf(g, __shfl_xor(g, 2, 64));
    tau_reg = g;
  }
  int base = (b * NP + r0 + row) * 20;
  for (int sel = 0; sel < 20; sel++) {
    float mybv = -__builtin_inff(); int mybi = 0x7fffffff, mybs = 0;
    #pragma unroll
    for (int s = 0; s < 20; s++) {
      bool better = lv[s] > mybv || (lv[s] == mybv && li[s] < mybi);
      if (better) { mybv = lv[s]; mybi = li[s]; mybs = s; }
    }
    float bv = mybv; int bi = mybi;
    float ov = __shfl_xor(bv, 1, 64); int oi = __shfl_xor(bi, 1, 64);
    if (ov > bv || (ov == bv && oi < bi)) { bv = ov; bi = oi; }
    ov = __shfl_xor(bv, 2, 64); oi = __shfl_xor(bi, 2, 64);
    if (ov > bv || (ov == bv && oi < bi)) { bv = ov; bi = oi; }
    if (sub == 0) idx_out[base + sel] = bi;
    if (bi == mybi) {
      #pragma unroll
      for (int s = 0; s < 20; s++)
        if (s == mybs) { lv[s] = -__builtin_inff(); li[s] = 0x7fffffff; }
    }
  }
}

__global__ __launch_bounds__(256) void knn_fused(
    const unsigned short* __restrict__ Hhi, const unsigned short* __restrict__ Hlo,
    const float* __restrict__ HH,
    const float* __restrict__ X, const float* __restrict__ CC,
    int* __restrict__ idx1, int* __restrict__ idx2) {
  __shared__ __attribute__((aligned(16))) unsigned char smem[36960];
  int id = blockIdx.x;                       // flat grid 1024
  int flavor = (id >> 8) & 1;                // slots {id,+256,+512,+768} ->
  int slot = (id & 255) | ((id >> 9) << 8);  // flavors {0,1,0,1} per CU
  int b = slot >> 6, xt = slot & 63;
  if (flavor == 0)
    knn64_body(smem, Hhi, Hlo, HH, idx1, xt, b);
  else
    knn3_body(smem, X, CC, idx2, xt, b);
}

// ---------------- K3: dg stage, 4 points/block, M=80 (zero padding) ----------
__global__ __launch_bounds__(256) void dg_stage(
    const unsigned short* __restrict__ hb16, const int* __restrict__ idx1,
    const unsigned short* __restrict__ w1b, const float* __restrict__ bia1,
    const unsigned short* __restrict__ w2b, const float* __restrict__ bia2,
    unsigned short* __restrict__ featb) {
  __shared__ unsigned short s_a[80][136];   // row stride 272 B (16B-aligned)
  __shared__ unsigned short s_v[80][136];
  __shared__ int s_nbf[80];
  int p0 = blockIdx.x * 4;                  // grid 8192; 4 pts share batch b
  int b = p0 >> 12, n0 = p0 & 4095;
  int t = threadIdx.x;
  int lane = t & 63, wave = t >> 6;
  if (t < 80) s_nbf[t] = idx1[p0 * 20 + t];
  __syncthreads();
  const unsigned short* hbb = hb16 + (size_t)b * NP * 64;
  {
    int cc = (t & 15) * 8;                  // uniform per-thread across iters
    int r00 = t >> 4;
    #pragma unroll
    for (int it = 0; it < 5; it++) {
      int row = r00 + it * 16;
      const unsigned short* src = (cc < 64)
        ? hbb + (size_t)s_nbf[row] * 64 + cc
        : hbb + (size_t)(n0 + row / 20) * 64 + (cc - 64);
      *(short8*)&s_a[row][cc] = *(const short8*)src;
    }
  }
  __syncthreads();
  int quad = lane >> 4, mrow = lane & 15;
  int nblock = wave * 32;
  // ---- dg1: A=s_a(80x128), W=w1b' ----
  {
    floatx4 acc[5][2];
    #pragma unroll
    for (int mt = 0; mt < 5; mt++) { acc[mt][0] = (floatx4)0.f; acc[mt][1] = (floatx4)0.f; }
    #pragma unroll
    for (int ks = 0; ks < 4; ks++) {
      int k0 = ks * 32 + quad * 8;
      short8 w0 = *(const short8*)(w1b + (nblock + mrow) * 128 + k0);
      short8 w1v = *(const short8*)(w1b + (nblock + 16 + mrow) * 128 + k0);
      #pragma unroll
      for (int mt = 0; mt < 5; mt++) {
        short8 a = *(short8*)&s_a[mt * 16 + mrow][k0];
        acc[mt][0] = mfma_bf16(a, w0, acc[mt][0]);
        acc[mt][1] = mfma_bf16(a, w1v, acc[mt][1]);
      }
    }
    #pragma unroll
    for (int ns = 0; ns < 2; ns++) {
      int o = nblock + ns * 16 + mrow;
      float bz = bia1[o];
      #pragma unroll
      for (int mt = 0; mt < 5; mt++)
        #pragma unroll
        for (int r = 0; r < 4; r++)
          s_v[mt * 16 + quad * 4 + r][o] = f2bf(fmaxf(acc[mt][ns][r] + bz, 0.f));
    }
  }
  __syncthreads();                          // s_v ready; all s_a reads done
  if (t < 128) {                            // maxpool1: u16 max (values >= 0)
    int pt = t >> 5, o4 = (t & 31) * 4;
    u16x4 mx = (u16x4)0;
    #pragma unroll
    for (int k = 0; k < 20; k++)
      mx = max4(mx, *(const u16x4*)&s_v[pt * 20 + k][o4]);
    *(u16x4*)&featb[(size_t)(p0 + pt) * 512 + o4] = mx;
  }
  // ---- dg2: A=s_v(80x128), W=w2b, relu -> s_a (reuse) ----
  {
    floatx4 acc[5][2];
    #pragma unroll
    for (int mt = 0; mt < 5; mt++) { acc[mt][0] = (floatx4)0.f; acc[mt][1] = (floatx4)0.f; }
    #pragma unroll
    for (int ks = 0; ks < 4; ks++) {
      int k0 = ks * 32 + quad * 8;
      short8 w0 = *(const short8*)(w2b + (nblock + mrow) * 128 + k0);
      short8 w1v = *(const short8*)(w2b + (nblock + 16 + mrow) * 128 + k0);
      #pragma unroll
      for (int mt = 0; mt < 5; mt++) {
        short8 a = *(short8*)&s_v[mt * 16 + mrow][k0];
        acc[mt][0] = mfma_bf16(a, w0, acc[mt][0]);
        acc[mt][1] = mfma_bf16(a, w1v, acc[mt][1]);
      }
    }
    #pragma unroll
    for (int ns = 0; ns < 2; ns++) {
      int o = nblock + ns * 16 + mrow;
      float bz = bia2[o];
      #pragma unroll
      for (int mt = 0; mt < 5; mt++)
        #pragma unroll
        for (int r = 0; r < 4; r++)
          s_a[mt * 16 + quad * 4 + r][o] = f2bf(fmaxf(acc[mt][ns][r] + bz, 0.f));
    }
  }
  __syncthreads();
  if (t < 128) {                            // maxpool2: u16 max
    int pt = t >> 5, o4 = (t & 31) * 4;
    u16x4 mx = (u16x4)0;
    #pragma unroll
    for (int k = 0; k < 20; k++)
      mx = max4(mx, *(const u16x4*)&s_a[pt * 20 + k][o4]);
    *(u16x4*)&featb[(size_t)(p0 + pt) * 512 + 128 + o4] = mx;
  }
}

// ---------------- K4: sn stage, 4 points/block, M=80 -------------------------
__global__ __launch_bounds__(256) void sn_stage(
    const int* __restrict__ idx2, const unsigned short* __restrict__ wb,
    const float* __restrict__ bias, unsigned short* __restrict__ featb) {
  __shared__ unsigned short s_a[80][264];   // row stride 528 B (16B-aligned)
  __shared__ int s_nbf[80];
  int p0 = blockIdx.x * 4;
  int b = p0 >> 12, n0 = p0 & 4095;
  int bb = b << 12;
  int t = threadIdx.x;
  int lane = t & 63, wave = t >> 6;
  if (t < 80) s_nbf[t] = idx2[p0 * 20 + t];
  __syncthreads();
  {
    int cc = (t & 31) * 8;                  // uniform per-thread
    int r00 = t >> 5;
    #pragma unroll
    for (int it = 0; it < 10; it++) {
      int row = r00 + it * 8;
      const unsigned short* src = (cc < 128)
        ? featb + (size_t)(bb + s_nbf[row]) * 512 + 128 + cc
        : featb + (size_t)(bb + n0 + row / 20) * 512 + cc;   // 128+(cc-128)
      *(short8*)&s_a[row][cc] = *(const short8*)src;
    }
  }
  __syncthreads();
  int quad = lane >> 4, mrow = lane & 15;
  int nblock = wave * 64;
  floatx4 acc[5][4];
  #pragma unroll
  for (int mt = 0; mt < 5; mt++)
    #pragma unroll
    for (int ns = 0; ns < 4; ns++) acc[mt][ns] = (floatx4)0.f;
  #pragma unroll
  for (int ks = 0; ks < 8; ks++) {
    int k0 = ks * 32 + quad * 8;
    short8 w[4];
    #pragma unroll
    for (int ns = 0; ns < 4; ns++)
      w[ns] = *(const short8*)(wb + (nblock + ns * 16 + mrow) * 256 + k0);
    #pragma unroll
    for (int mt = 0; mt < 5; mt++) {
      short8 a = *(short8*)&s_a[mt * 16 + mrow][k0];
      #pragma unroll
      for (int ns = 0; ns < 4; ns++)
        acc[mt][ns] = mfma_bf16(a, w[ns], acc[mt][ns]);
    }
  }
  __syncthreads();                          // all s_a reads done
  #pragma unroll
  for (int ns = 0; ns < 4; ns++) {
    int o = nblock + ns * 16 + mrow;
    float bz = bias[o];
    #pragma unroll
    for (int mt = 0; mt < 5; mt++)
      #pragma unroll
      for (int r = 0; r < 4; r++)
        s_a[mt * 16 + quad * 4 + r][o] = f2bf(fmaxf(acc[mt][ns][r] + bz, 0.f));
  }
  __syncthreads();
  {                                         // maxpool: u16 max (values >= 0)
    int pt = t >> 6, o4 = (t & 63) * 4;
    u16x4 mx = (u16x4)0;
    #pragma unroll
    for (int k = 0; k < 20; k++)
      mx = max4(mx, *(const u16x4*)&s_a[pt * 20 + k][o4]);
    *(u16x4*)&featb[(size_t)(p0 + pt) * 512 + 256 + o4] = mx;
  }
}

// ---------------- K5: conv3 GEMM ---------------------------------------------
__global__ __launch_bounds__(256) void conv3_gemm(
    const unsigned short* __restrict__ w3b, const unsigned short* __restrict__ featb,
    const float* __restrict__ b3, float* __restrict__ out) {
  __shared__ unsigned short s_a[128][40];
  __shared__ unsigned short s_b[128][40];
  int o0 = blockIdx.x * 128, p0 = blockIdx.y * 128;
  int t = threadIdx.x, lane = t & 63, wave = t >> 6;
  int wy = wave >> 1, wx = wave & 1;
  int quad = lane >> 4, l15 = lane & 15;
  floatx4 acc[4][4];
  #pragma unroll
  for (int i = 0; i < 4; i++)
    #pragma unroll
    for (int j = 0; j < 4; j++) acc[i][j] = (floatx4)0.f;
  for (int kc = 0; kc < 16; kc++) {
    __syncthreads();
    for (int e = t; e < 512; e += 256) {
      int r = e >> 2, c8 = (e & 3) * 8;
      *(short8*)&s_a[r][c8] = *(const short8*)(w3b + (size_t)(o0 + r) * 512 + kc * 32 + c8);
    }
    for (int e = t; e < 512; e += 256) {
      int r = e >> 2, c8 = (e & 3) * 8;
      *(short8*)&s_b[r][c8] = *(const short8*)(featb + (size_t)(p0 + r) * 512 + kc * 32 + c8);
    }
    __syncthreads();
    int k0 = quad * 8;
    short8 af[4], bfr[4];
    #pragma unroll
    for (int i = 0; i < 4; i++) af[i] = *(short8*)&s_a[wy * 64 + i * 16 + l15][k0];
    #pragma unroll
    for (int j = 0; j < 4; j++) bfr[j] = *(short8*)&s_b[wx * 64 + j * 16 + l15][k0];
    #pragma unroll
    for (int i = 0; i < 4; i++)
      #pragma unroll
      for (int j = 0; j < 4; j++) acc[i][j] = mfma_bf16(af[i], bfr[j], acc[i][j]);
  }
  #pragma unroll
  for (int i = 0; i < 4; i++)
    #pragma unroll
    for (int j = 0; j < 4; j++) {
      int pl = p0 + wx * 64 + j * 16 + l15;
      int bI = pl >> 12, n = pl & 4095;
      #pragma unroll
      for (int r = 0; r < 4; r++) {
        int o = o0 + wy * 64 + i * 16 + quad * 4 + r;
        out[(size_t)(bI * 1024 + o) * 4096 + n] = fmaxf(acc[i][j][r] + b3[o], 0.f);
      }
    }
}

// ---------------- launcher ---------------------------------------------------
extern "C" void kernel_launch(void* const* d_in, const int* in_sizes, int n_in,
                              void* d_out, int out_size, void* d_ws, size_t ws_size,
                              hipStream_t stream) {
  const float* x    = (const float*)d_in[0];
  const float* w1   = (const float*)d_in[1];
  const float* b1   = (const float*)d_in[2];
  const float* w2   = (const float*)d_in[3];
  const float* b2   = (const float*)d_in[4];
  const float* wdg1 = (const float*)d_in[5];
  const float* bdg1 = (const float*)d_in[6];
  const float* wdg2 = (const float*)d_in[7];
  const float* bdg2 = (const float*)d_in[8];
  const float* wsn1 = (const float*)d_in[9];
  const float* bsn1 = (const float*)d_in[10];
  const float* w3   = (const float*)d_in[11];
  const float* b3   = (const float*)d_in[12];

  float* ws = (float*)d_ws;                 // offsets in float slots
  unsigned short* hlo16 = (unsigned short*)ws;               // 2,097,152 bf16 (1,048,576 slots)
  float* hh = ws + 2097152;                 //    32,768
  float* cc = ws + 2129920;                 //    32,768
  int* idx1 = (int*)(ws + 2162688);         //   655,360
  int* idx2 = (int*)(ws + 2818048);         //   655,360
  unsigned short* featb = (unsigned short*)(ws + 3473408);   // 16,777,216 bf16
  unsigned short* wdg1b = (unsigned short*)(ws + 11862016);
  unsigned short* wdg2b = (unsigned short*)(ws + 11870208);
  unsigned short* wsn1b = (unsigned short*)(ws + 11878400);
  unsigned short* w3b   = (unsigned short*)(ws + 11911168);
  unsigned short* hb16  = (unsigned short*)(ws + 12173312); // 2,097,152 bf16

  conv12_cvt<<<10240, 256, 0, stream>>>(x, w1, b1, w2, b2, hb16, hlo16, hh, cc,
                                        wdg1, wdg1b, wdg2, wdg2b,
                                        wsn1, wsn1b, w3, w3b);
  knn_fused<<<1024, 256, 0, stream>>>(hb16, hlo16, hh, x, cc, idx1, idx2);
  dg_stage<<<8192, 256, 0, stream>>>(hb16, idx1, wdg1b, bdg1, wdg2b, bdg2, featb);
  sn_stage<<<8192, 256, 0, stream>>>(idx2, wsn1b, bsn1, featb);
  conv3_gemm<<<dim3(8, 256), 256, 0, stream>>>(w3b, featb, b3, (float*)d_out);
}